// Round 14
// baseline (15847.836 us; speedup 1.0000x reference)
//
#include <hip/hip_runtime.h>
#include <hip/hip_bf16.h>
#include <cstddef>
#include <cstdint>

// B=32, T=2048, D=64, H=256, O=32, 4H=1024
#define BB 32
#define TT 2048
#define DD 64
#define HH 256
#define OO 32
#define NBLK 8   // blocks per layer

#define OUT_ELEMS (BB*TT*OO)
#define HN_OFF OUT_ELEMS
#define CN_OFF (HN_OFF + 2*BB*HH)

// ---------------- workspace byte offsets (round-5 map, unchanged) ----------------
#define O_XBF   ((size_t)0)                     // x bf16 [T][B][64]
#define O_H0    ((size_t)8388608)               // h0buf bf16 [2049][32][256]
#define O_XH1   ((size_t)41959424)              // xh1 bf16 [2049][32][512]
#define O_WP0   ((size_t)109101056)             // Wperm0 bf16 [1024][320]
#define O_WP1   ((size_t)109756416)             // Wperm1 bf16 [1024][512]
#define O_B0    ((size_t)110804992)             // bias0 f32 [1024]
#define O_B1    ((size_t)110809088)             // bias1 f32 [1024]
#define O_WD0T  ((size_t)110813184)             // [256][256] f32 transposed
#define O_WD1T  ((size_t)111075328)
#define O_WOUT  ((size_t)111337472)             // [256][32] f32
#define O_TAG   ((size_t)111370240)             // per-WAVE tags (prep zeroes 16KB)
// tagsL0: half h at O_TAG + h*128 (32 ints, idx = j*4+hr)
// tagsL1: half h at O_TAG + 1024 + h*128

typedef short short8 __attribute__((ext_vector_type(8)));
typedef float f32x4 __attribute__((ext_vector_type(4)));

__device__ __forceinline__ float sigm_(float x){ return 1.0f/(1.0f+__expf(-x)); }
__device__ __forceinline__ float tanhf_(float x){
    float xc = fminf(fmaxf(x, -15.0f), 15.0f);
    float e = __expf(2.0f*xc);
    return (e-1.0f)/(e+1.0f);
}
__device__ __forceinline__ unsigned short f2bf(float f){
    __hip_bfloat16 h = __float2bfloat16(f);
    return *reinterpret_cast<unsigned short*>(&h);
}
__device__ __forceinline__ unsigned int pack2(float a, float b){
    return (unsigned int)f2bf(a) | ((unsigned int)f2bf(b) << 16);
}
__device__ __forceinline__ short8 ld8(const unsigned short* p){
    return *reinterpret_cast<const short8*>(p);
}

// Poll the 32 per-wave tags of one half: lanes 0..31 each load one tag in a
// single wave load (2 cache lines).  Agent-scope atomic load (reused-address
// pattern proven r4/r5/r13).  Capped: bugs fail validation, not the limit.
__device__ __forceinline__ void pollTags(const int* tags, int tgt, int lane){
    int it = 0;
    while (true) {
        int v = tgt;
        if (lane < 32)
            v = __hip_atomic_load(tags + lane, __ATOMIC_RELAXED, __HIP_MEMORY_SCOPE_AGENT);
        if (__all(v >= tgt)) break;
        __builtin_amdgcn_s_sleep(1);
        if (++it > (1<<16)) break;
    }
    asm volatile("" ::: "memory");
}

// Lane-split poll of two 32-tag arrays in one load per round:
// lanes 0..31 watch t0[lane] >= tgt0, lanes 32..63 watch t1[lane-32] >= tgt1.
__device__ __forceinline__ void pollTags2(const int* t0a, int tgt0,
                                          const int* t1a, int tgt1, int lane){
    const int* p = (lane < 32) ? (t0a + lane) : (t1a + (lane - 32));
    const int tgt = (lane < 32) ? tgt0 : tgt1;
    int it = 0;
    while (true) {
        int v = __hip_atomic_load(p, __ATOMIC_RELAXED, __HIP_MEMORY_SCOPE_AGENT);
        if (__all(v >= tgt)) break;
        __builtin_amdgcn_s_sleep(1);
        if (++it > (1<<16)) break;
    }
    asm volatile("" ::: "memory");
}

// ---------------------------------------------------------------------------
// Prep (identical to rounds 4-5/13; zeroes the tag region).
// ---------------------------------------------------------------------------
__global__ void prep_kernel(const float* __restrict__ x, const float* __restrict__ h0,
    const float* __restrict__ Wih0, const float* __restrict__ Whh0,
    const float* __restrict__ bih0, const float* __restrict__ bhh0,
    const float* __restrict__ Wih1, const float* __restrict__ Whh1,
    const float* __restrict__ bih1, const float* __restrict__ bhh1,
    const float* __restrict__ Wd0, const float* __restrict__ Wd1,
    const float* __restrict__ Wout, char* __restrict__ ws)
{
    int i = blockIdx.x*256 + threadIdx.x;
    if (i < 4194304) {  // x [B][T][D] -> xbf2 [T][B][D] bf16
        int t = i >> 11, rem = i & 2047, b = rem >> 6, d = rem & 63;
        ((unsigned short*)(ws+O_XBF))[i] = f2bf(x[(size_t)b*131072 + t*64 + d]);
        return;
    }
    i -= 4194304;
    if (i < 327680) {   // Wperm0 [1024][320]
        int R = i / 320, k = i - R*320;
        int lrow = R & 15, s = (R>>4)&1, hr = (R>>5)&3, jj = R>>7;
        int gate = 2*s + (lrow>>3);
        int h = 32*jj + 8*hr + (lrow&7);
        int src = 256*gate + h;
        float v = (k < 64) ? Wih0[src*64 + k] : Whh0[src*256 + (k-64)];
        ((unsigned short*)(ws+O_WP0))[i] = f2bf(v);
        return;
    }
    i -= 327680;
    if (i < 524288) {   // Wperm1 [1024][512]
        int R = i >> 9, k = i & 511;
        int lrow = R & 15, s = (R>>4)&1, hr = (R>>5)&3, jj = R>>7;
        int gate = 2*s + (lrow>>3);
        int h = 32*jj + 8*hr + (lrow&7);
        int src = 256*gate + h;
        float v = (k < 256) ? Wih1[src*256 + k] : Whh1[src*256 + (k-256)];
        ((unsigned short*)(ws+O_WP1))[i] = f2bf(v);
        return;
    }
    i -= 524288;
    if (i < 1024) { ((float*)(ws+O_B0))[i] = bih0[i] + bhh0[i]; return; }
    i -= 1024;
    if (i < 1024) { ((float*)(ws+O_B1))[i] = bih1[i] + bhh1[i]; return; }
    i -= 1024;
    if (i < 8192) { ((unsigned short*)(ws+O_H0))[i] = f2bf(h0[i]); return; }   // h0buf[0]
    i -= 8192;
    if (i < 8192) {     // xh1[0][b][256+h] = h0[1][b][h]
        int b = i >> 8, h = i & 255;
        ((unsigned short*)(ws+O_XH1))[b*512 + 256 + h] = f2bf(h0[8192 + i]);
        return;
    }
    i -= 8192;
    if (i < 65536) { int o = i & 255, h = i >> 8; ((float*)(ws+O_WD0T))[i] = Wd0[o*256 + h]; return; }
    i -= 65536;
    if (i < 65536) { int o = i & 255, h = i >> 8; ((float*)(ws+O_WD1T))[i] = Wd1[o*256 + h]; return; }
    i -= 65536;
    if (i < 8192) { int o = i & 31, h = i >> 5; ((float*)(ws+O_WOUT))[i] = Wout[o*256 + h]; return; }
    i -= 8192;
    if (i < 4096) { ((int*)(ws+O_TAG))[i] = 0; return; }   // tag region (16KB)
}

// ---------------------------------------------------------------------------
// Persistent LSTM, PER-WAVE publication (minimal rendezvous chain).
// 8 blocks/layer x 512 threads (8 waves).  Wave (hr,bh) of block j owns all
// 4 gates for h-range [32j+8hr,+8) x batches [16bh,+16).  Per step:
// [pre-poll MFMAs on static inputs] -> one-wave-load 32-tag poll ->
// B-frag loads -> MFMAs -> shfl_xor register gate-combine -> agent stores ->
// per-wave s_waitcnt vmcnt(0) -> lane0 publishes this wave's tag.
// NO barriers, NO block flags, NO LDS.  Tag semantics: tag[(L,half,j,hr)]=v
// means that wave's slots <= v are MALL-visible (slot 0 from prep is free).
// mfma_f32_16x16x32_bf16: A lane l -> A[row=l&15][k=(l>>4)*8+j];
//                         B lane l -> B[k][col=l&15];
//                         D lane l -> D[row=(l>>4)*4+r][col=l&15].
// ---------------------------------------------------------------------------
template<int L>
__device__ void lstm_body(int j, char* ws, const float* __restrict__ c0_in,
                          float* __restrict__ out)
{
    constexpr int KK  = L ? 512 : 320;
    constexpr int NKT = KK / 32;

    const int tid  = threadIdx.x;
    const int wv   = tid >> 6;
    const int lane = tid & 63;
    const int bh   = wv >> 2;          // batch half
    const int hr   = wv & 3;
    const int lrow = lane & 15;
    const int q    = lane >> 4;
    const int koff = q * 8;
    const int qe   = q & 1;
    const int fb   = bh*16 + lrow;
    const int hbase= 32*j + 8*hr + 4*qe;
    const bool lo  = (lane < 32);

    const unsigned short* Wp = (const unsigned short*)(ws + (L ? O_WP1 : O_WP0));
    const float* bias = (const float*)(ws + (L ? O_B1 : O_B0));

    const int wavebase = (j*4 + hr) * 32;
    short8 a0[NKT], a1[NKT];
#pragma unroll
    for (int kk = 0; kk < NKT; ++kk) {
        a0[kk] = ld8(Wp + (size_t)(wavebase +      lrow)*KK + kk*32 + koff);
        a1[kk] = ld8(Wp + (size_t)(wavebase + 16 + lrow)*KK + kk*32 + koff);
    }

    float bi[4], bf_[4], bg[4], bo[4], c[4], hv[4];
#pragma unroll
    for (int r = 0; r < 4; ++r) {
        int hg = hbase + r;
        bi[r] = bias[hg];       bf_[r] = bias[256+hg];
        bg[r] = bias[512+hg];   bo[r]  = bias[768+hg];
        c[r]  = c0_in[(size_t)L*8192 + fb*256 + hg];
        hv[r] = 0.f;
    }

    // per-wave tag arrays: tagsL0 half at O_TAG + bh*128; tagsL1 at +1024
    int* T0h = (int*)(ws + O_TAG) + bh*32;
    int* T1h = (int*)(ws + O_TAG + 1024) + bh*32;
    int* mytag = (L ? T1h : T0h) + (j*4 + hr);

    const unsigned short* xb = (const unsigned short*)(ws + O_XBF) + fb*64  + koff;
    const unsigned short* hb = (const unsigned short*)(ws + O_H0)  + fb*256 + koff;
    const unsigned short* xh = (const unsigned short*)(ws + O_XH1) + fb*512 + koff;

    unsigned long long* stA;
    unsigned long long* stB = nullptr;
    if (L == 0) {
        stA = (unsigned long long*)((unsigned short*)(ws + O_H0)  + (size_t)8192 + fb*256 + hbase);
        stB = (unsigned long long*)((unsigned short*)(ws + O_XH1) + (size_t)fb*512 + hbase);
    } else {
        stA = (unsigned long long*)((unsigned short*)(ws + O_XH1) + (size_t)16384 + fb*512 + 256 + hbase);
    }

    for (int t = 0; t < TT; ++t) {
        f32x4 A0 = {0.f,0.f,0.f,0.f}, A1 = {0.f,0.f,0.f,0.f};

        if (L == 0) {
            // x-part: static input -> load + 4 MFMAs BEFORE the poll
            short8 bx0 = ld8(xb), bx1 = ld8(xb + 32);
            A0 = __builtin_amdgcn_mfma_f32_16x16x32_bf16(a0[0], bx0, A0, 0,0,0);
            A1 = __builtin_amdgcn_mfma_f32_16x16x32_bf16(a1[0], bx0, A1, 0,0,0);
            A0 = __builtin_amdgcn_mfma_f32_16x16x32_bf16(a0[1], bx1, A0, 0,0,0);
            A1 = __builtin_amdgcn_mfma_f32_16x16x32_bf16(a1[1], bx1, A1, 0,0,0);

            pollTags(T0h, t, lane);   // this half's h0[t] visible (32 waves)

            short8 b[8];
#pragma unroll
            for (int kk = 0; kk < 8; ++kk) b[kk] = ld8(hb + 32*kk);
#pragma unroll
            for (int kk = 0; kk < 8; ++kk) {
                A0 = __builtin_amdgcn_mfma_f32_16x16x32_bf16(a0[2+kk], b[kk], A0, 0,0,0);
                A1 = __builtin_amdgcn_mfma_f32_16x16x32_bf16(a1[2+kk], b[kk], A1, 0,0,0);
            }
        } else {
            // y0[t] = h0 slot t+1 (tags0 >= t+1); h1[t] = slot t (tags1 >= t)
            pollTags2(T0h, t+1, T1h, t, lane);

            short8 b[8];
#pragma unroll
            for (int kk = 0; kk < 8; ++kk) b[kk] = ld8(xh + 32*kk);
#pragma unroll
            for (int kk = 0; kk < 8; ++kk) {
                A0 = __builtin_amdgcn_mfma_f32_16x16x32_bf16(a0[kk], b[kk], A0, 0,0,0);
                A1 = __builtin_amdgcn_mfma_f32_16x16x32_bf16(a1[kk], b[kk], A1, 0,0,0);
            }
#pragma unroll
            for (int kk = 0; kk < 8; ++kk) b[kk] = ld8(xh + 256 + 32*kk);
#pragma unroll
            for (int kk = 0; kk < 8; ++kk) {
                A0 = __builtin_amdgcn_mfma_f32_16x16x32_bf16(a0[8+kk], b[kk], A0, 0,0,0);
                A1 = __builtin_amdgcn_mfma_f32_16x16x32_bf16(a1[8+kk], b[kk], A1, 0,0,0);
            }
        }

#pragma unroll
        for (int r = 0; r < 4; ++r) {
            float x0 = A0[r], y0 = __shfl_xor(x0, 32, 64);
            float x1 = A1[r], y1 = __shfl_xor(x1, 32, 64);
            float gi = (lo ? x0 : y0) + bi[r];
            float gf = (lo ? y0 : x0) + bf_[r];
            float gg = (lo ? x1 : y1) + bg[r];
            float go = (lo ? y1 : x1) + bo[r];
            float iv = sigm_(gi), fv = sigm_(gf), gv = tanhf_(gg), ov = sigm_(go);
            c[r]  = fv*c[r] + iv*gv;
            hv[r] = ov * tanhf_(c[r]);
        }

        unsigned long long w =
            (unsigned long long)pack2(hv[0], hv[1]) |
            ((unsigned long long)pack2(hv[2], hv[3]) << 32);

        if (L == 0) {
            if (lo) __hip_atomic_store(stA, w, __ATOMIC_RELAXED, __HIP_MEMORY_SCOPE_AGENT);
            else    __hip_atomic_store(stB, w, __ATOMIC_RELAXED, __HIP_MEMORY_SCOPE_AGENT);
        } else {
            if (lo) __hip_atomic_store(stA, w, __ATOMIC_RELAXED, __HIP_MEMORY_SCOPE_AGENT);
        }

        // minimal rendezvous: this wave's stores drained -> publish its tag.
        asm volatile("s_waitcnt vmcnt(0)" ::: "memory");
        if (lane == 0)
            __hip_atomic_store(mytag, t+1, __ATOMIC_RELAXED, __HIP_MEMORY_SCOPE_AGENT);

        xb += 2048; hb += 8192; xh += 16384;
        stA += (L ? 4096 : 2048);
        if (L == 0) stB += 4096;
    }

    if (lo) {
#pragma unroll
        for (int r = 0; r < 4; ++r) {
            out[HN_OFF + (size_t)L*8192 + fb*256 + hbase + r] = hv[r];
            out[CN_OFF + (size_t)L*8192 + fb*256 + hbase + r] = c[r];
        }
    }
}

__global__ __launch_bounds__(512, 2) void lstm_fused(char* ws,
                                                     const float* __restrict__ c0_in,
                                                     float* __restrict__ out)
{
    if (blockIdx.x < NBLK) lstm_body<0>(blockIdx.x, ws, c0_in, out);
    else                   lstm_body<1>(blockIdx.x - NBLK, ws, c0_in, out);
}

// ---------------------------------------------------------------------------
// Fused dense head (identical to round 5).
// ---------------------------------------------------------------------------
__global__ __launch_bounds__(256) void head_kernel(const char* __restrict__ ws,
    const float* __restrict__ bd0, const float* __restrict__ bd1,
    const float* __restrict__ bout, float* __restrict__ out)
{
    const __hip_bfloat16* xh1 = (const __hip_bfloat16*)(ws + O_XH1);
    const float* Wd0T  = (const float*)(ws + O_WD0T);
    const float* Wd1T  = (const float*)(ws + O_WD1T);
    const float* WoutT = (const float*)(ws + O_WOUT);

    __shared__ float buf0[16][256];
    __shared__ float buf1[16][256];
    const int row0 = blockIdx.x * 16;
    const int tid = threadIdx.x;

#pragma unroll
    for (int i = 0; i < 16; ++i) {
        int r = row0 + i;
        int b = r >> 11, t = r & 2047;
        buf0[i][tid] = __bfloat162float(xh1[(size_t)(t+1)*16384 + b*512 + 256 + tid]);
    }
    __syncthreads();

    {   // stage 1: Linear+ReLU
        float acc[16];
        float bv = bd0[tid];
#pragma unroll
        for (int r = 0; r < 16; ++r) acc[r] = bv;
        for (int h = 0; h < 256; ++h) {
            float w = Wd0T[h*256 + tid];
#pragma unroll
            for (int r = 0; r < 16; ++r) acc[r] += w * buf0[r][h];
        }
        __syncthreads();
#pragma unroll
        for (int r = 0; r < 16; ++r) buf1[r][tid] = fmaxf(acc[r], 0.0f);
    }
    __syncthreads();

    {   // stage 2: Linear+ReLU
        float acc[16];
        float bv = bd1[tid];
#pragma unroll
        for (int r = 0; r < 16; ++r) acc[r] = bv;
        for (int h = 0; h < 256; ++h) {
            float w = Wd1T[h*256 + tid];
#pragma unroll
            for (int r = 0; r < 16; ++r) acc[r] += w * buf1[r][h];
        }
        __syncthreads();
#pragma unroll
        for (int r = 0; r < 16; ++r) buf0[r][tid] = fmaxf(acc[r], 0.0f);
    }
    __syncthreads();

    {   // stage 3: output Linear
        const int o = tid & 31;
        const int rr = tid >> 5;
        float a0 = bout[o], a1 = bout[o];
        for (int h = 0; h < 256; ++h) {
            float w = WoutT[h*32 + o];
            a0 += w * buf0[rr*2 + 0][h];
            a1 += w * buf0[rr*2 + 1][h];
        }
        out[(size_t)(row0 + rr*2 + 0)*32 + o] = a0;
        out[(size_t)(row0 + rr*2 + 1)*32 + o] = a1;
    }
}

// ---------------------------------------------------------------------------
extern "C" void kernel_launch(void* const* d_in, const int* in_sizes, int n_in,
                              void* d_out, int out_size, void* d_ws, size_t ws_size,
                              hipStream_t stream) {
    const float* x    = (const float*)d_in[0];
    const float* h0   = (const float*)d_in[1];
    const float* c0   = (const float*)d_in[2];
    const float* Wih0 = (const float*)d_in[3];
    const float* Whh0 = (const float*)d_in[4];
    const float* bih0 = (const float*)d_in[5];
    const float* bhh0 = (const float*)d_in[6];
    const float* Wih1 = (const float*)d_in[7];
    const float* Whh1 = (const float*)d_in[8];
    const float* bih1 = (const float*)d_in[9];
    const float* bhh1 = (const float*)d_in[10];
    const float* Wd0  = (const float*)d_in[11];
    const float* bd0  = (const float*)d_in[12];
    const float* Wd1  = (const float*)d_in[13];
    const float* bd1  = (const float*)d_in[14];
    const float* Wout = (const float*)d_in[15];
    const float* bout = (const float*)d_in[16];

    char* ws = (char*)d_ws;
    float* out = (float*)d_out;

    prep_kernel<<<20344, 256, 0, stream>>>(x, h0, Wih0, Whh0, bih0, bhh0,
                                           Wih1, Whh1, bih1, bhh1,
                                           Wd0, Wd1, Wout, ws);
    lstm_fused<<<2*NBLK, 512, 0, stream>>>(ws, c0, out);
    head_kernel<<<4096, 256, 0, stream>>>(ws, bd0, bd1, bout, out);
}

// Round 15
// 12377.911 us; speedup vs baseline: 1.2803x; 1.2803x over previous
//
#include <hip/hip_runtime.h>
#include <hip/hip_bf16.h>
#include <cstddef>
#include <cstdint>

// B=32, T=2048, D=64, H=256, O=32, 4H=1024
#define BB 32
#define TT 2048
#define DD 64
#define HH 256
#define OO 32
#define NBLK 8   // blocks per layer

#define OUT_ELEMS (BB*TT*OO)
#define HN_OFF OUT_ELEMS
#define CN_OFF (HN_OFF + 2*BB*HH)

// ---------------- workspace byte offsets ----------------
#define O_XBF   ((size_t)0)                     // x bf16 [T][B][64]
#define O_H0    ((size_t)8388608)               // h0buf bf16 [2049][32][256]
#define O_XH1   ((size_t)41959424)              // xh1 bf16 [2049][32][512]
#define O_WP0   ((size_t)109101056)             // Wperm0 bf16 [1024][320]
#define O_WP1   ((size_t)109756416)             // Wperm1 bf16 [1024][512]
#define O_B0    ((size_t)110804992)             // bias0 f32 [1024]
#define O_B1    ((size_t)110809088)             // bias1 f32 [1024]
#define O_WD0T  ((size_t)110813184)             // [256][256] f32 transposed
#define O_WD1T  ((size_t)111075328)
#define O_WOUT  ((size_t)111337472)             // [256][32] f32
#define O_D0    ((size_t)111370240)             // flags layer0: int[8]
#define O_D1    (O_D0 + 256)                    // flags layer1: int[8]
#define DONE_IDX 128                            // done counter int at O_D0+512
// prep zeroes 16KB of ints starting at O_D0 (covers flags + done)

typedef short short8 __attribute__((ext_vector_type(8)));
typedef float f32x4 __attribute__((ext_vector_type(4)));
typedef unsigned int uint4v __attribute__((ext_vector_type(4)));

__device__ __forceinline__ float sigm_(float x){ return 1.0f/(1.0f+__expf(-x)); }
__device__ __forceinline__ float tanhf_(float x){
    float xc = fminf(fmaxf(x, -15.0f), 15.0f);
    float e = __expf(2.0f*xc);
    return (e-1.0f)/(e+1.0f);
}
__device__ __forceinline__ unsigned short f2bf(float f){
    __hip_bfloat16 h = __float2bfloat16(f);
    return *reinterpret_cast<unsigned short*>(&h);
}
__device__ __forceinline__ unsigned int pack2(float a, float b){
    return (unsigned int)f2bf(a) | ((unsigned int)f2bf(b) << 16);
}
__device__ __forceinline__ short8 ld8(const unsigned short* p){
    return *reinterpret_cast<const short8*>(p);
}

// Single-poller primitives (proven rounds 4-5-8).
__device__ __forceinline__ void pollLine(const int* flags, int tgt, int lane){
    int it = 0;
    while (true) {
        int v = tgt;
        if (lane < NBLK)
            v = __hip_atomic_load(flags + lane, __ATOMIC_RELAXED, __HIP_MEMORY_SCOPE_AGENT);
        if (__all(v >= tgt)) break;
        __builtin_amdgcn_s_sleep(1);
        if (++it > (1<<16)) break;
    }
    asm volatile("" ::: "memory");
}

__device__ __forceinline__ void pollTwo(const int* f0, int t0,
                                        const int* f1, int t1, int lane){
    const int* p = (lane < 8) ? (f0 + lane) : (f1 + (lane - 8));
    const int tgt = (lane < 8) ? t0 : t1;
    int it = 0;
    while (true) {
        int v = tgt;
        if (lane < 16)
            v = __hip_atomic_load(p, __ATOMIC_RELAXED, __HIP_MEMORY_SCOPE_AGENT);
        if (__all(v >= tgt)) break;
        __builtin_amdgcn_s_sleep(1);
        if (++it > (1<<16)) break;
    }
    asm volatile("" ::: "memory");
}

// ---------------------------------------------------------------------------
// Prep (identical to rounds 4-5-8).
// ---------------------------------------------------------------------------
__global__ void prep_kernel(const float* __restrict__ x, const float* __restrict__ h0,
    const float* __restrict__ Wih0, const float* __restrict__ Whh0,
    const float* __restrict__ bih0, const float* __restrict__ bhh0,
    const float* __restrict__ Wih1, const float* __restrict__ Whh1,
    const float* __restrict__ bih1, const float* __restrict__ bhh1,
    const float* __restrict__ Wd0, const float* __restrict__ Wd1,
    const float* __restrict__ Wout, char* __restrict__ ws)
{
    int i = blockIdx.x*256 + threadIdx.x;
    if (i < 4194304) {  // x [B][T][D] -> xbf2 [T][B][D] bf16
        int t = i >> 11, rem = i & 2047, b = rem >> 6, d = rem & 63;
        ((unsigned short*)(ws+O_XBF))[i] = f2bf(x[(size_t)b*131072 + t*64 + d]);
        return;
    }
    i -= 4194304;
    if (i < 327680) {   // Wperm0 [1024][320]
        int R = i / 320, k = i - R*320;
        int lrow = R & 15, s = (R>>4)&1, hr = (R>>5)&3, jj = R>>7;
        int gate = 2*s + (lrow>>3);
        int h = 32*jj + 8*hr + (lrow&7);
        int src = 256*gate + h;
        float v = (k < 64) ? Wih0[src*64 + k] : Whh0[src*256 + (k-64)];
        ((unsigned short*)(ws+O_WP0))[i] = f2bf(v);
        return;
    }
    i -= 327680;
    if (i < 524288) {   // Wperm1 [1024][512]
        int R = i >> 9, k = i & 511;
        int lrow = R & 15, s = (R>>4)&1, hr = (R>>5)&3, jj = R>>7;
        int gate = 2*s + (lrow>>3);
        int h = 32*jj + 8*hr + (lrow&7);
        int src = 256*gate + h;
        float v = (k < 256) ? Wih1[src*256 + k] : Whh1[src*256 + (k-256)];
        ((unsigned short*)(ws+O_WP1))[i] = f2bf(v);
        return;
    }
    i -= 524288;
    if (i < 1024) { ((float*)(ws+O_B0))[i] = bih0[i] + bhh0[i]; return; }
    i -= 1024;
    if (i < 1024) { ((float*)(ws+O_B1))[i] = bih1[i] + bhh1[i]; return; }
    i -= 1024;
    if (i < 8192) { ((unsigned short*)(ws+O_H0))[i] = f2bf(h0[i]); return; }   // h0buf[0]
    i -= 8192;
    if (i < 8192) {     // xh1[0][b][256+h] = h0[1][b][h]
        int b = i >> 8, h = i & 255;
        ((unsigned short*)(ws+O_XH1))[b*512 + 256 + h] = f2bf(h0[8192 + i]);
        return;
    }
    i -= 8192;
    if (i < 65536) { int o = i & 255, h = i >> 8; ((float*)(ws+O_WD0T))[i] = Wd0[o*256 + h]; return; }
    i -= 65536;
    if (i < 65536) { int o = i & 255, h = i >> 8; ((float*)(ws+O_WD1T))[i] = Wd1[o*256 + h]; return; }
    i -= 65536;
    if (i < 8192) { int o = i & 31, h = i >> 5; ((float*)(ws+O_WOUT))[i] = Wout[o*256 + h]; return; }
    i -= 8192;
    if (i < 4096) { ((int*)(ws+O_D0))[i] = 0; return; }   // flags + done
}

// ---------------------------------------------------------------------------
// Persistent LSTM worker body (byte-identical to rounds 5/8, both PASSED).
// ---------------------------------------------------------------------------
template<int L>
__device__ void lstm_body(int j, char* ws, const float* __restrict__ c0_in,
                          float* __restrict__ out)
{
    constexpr int KK  = L ? 512 : 320;
    constexpr int NKT = KK / 32;

    const int tid  = threadIdx.x;
    const int wv   = tid >> 6;
    const int lane = tid & 63;
    const int bh   = wv >> 2;
    const int hr   = wv & 3;
    const int lrow = lane & 15;
    const int q    = lane >> 4;
    const int koff = q * 8;
    const int qe   = q & 1;
    const int fb   = bh*16 + lrow;
    const int hbase= 32*j + 8*hr + 4*qe;
    const bool lo  = (lane < 32);

    const unsigned short* Wp = (const unsigned short*)(ws + (L ? O_WP1 : O_WP0));
    const float* bias = (const float*)(ws + (L ? O_B1 : O_B0));

    const int wavebase = (j*4 + hr) * 32;
    short8 a0[NKT], a1[NKT];
#pragma unroll
    for (int kk = 0; kk < NKT; ++kk) {
        a0[kk] = ld8(Wp + (size_t)(wavebase +      lrow)*KK + kk*32 + koff);
        a1[kk] = ld8(Wp + (size_t)(wavebase + 16 + lrow)*KK + kk*32 + koff);
    }

    float bi[4], bf_[4], bg[4], bo[4], c[4], hv[4];
#pragma unroll
    for (int r = 0; r < 4; ++r) {
        int hg = hbase + r;
        bi[r] = bias[hg];       bf_[r] = bias[256+hg];
        bg[r] = bias[512+hg];   bo[r]  = bias[768+hg];
        c[r]  = c0_in[(size_t)L*8192 + fb*256 + hg];
        hv[r] = 0.f;
    }

    int* flags0 = (int*)(ws + O_D0);
    int* flags1 = (int*)(ws + O_D1);
    int* myflag = (L ? flags1 : flags0) + j;

    const unsigned short* xb = (const unsigned short*)(ws + O_XBF) + fb*64  + koff;
    const unsigned short* hb = (const unsigned short*)(ws + O_H0)  + fb*256 + koff;
    const unsigned short* xh = (const unsigned short*)(ws + O_XH1) + fb*512 + koff;

    unsigned long long* stA;
    unsigned long long* stB = nullptr;
    if (L == 0) {
        stA = (unsigned long long*)((unsigned short*)(ws + O_H0)  + (size_t)8192 + fb*256 + hbase);
        stB = (unsigned long long*)((unsigned short*)(ws + O_XH1) + (size_t)fb*512 + hbase);
    } else {
        stA = (unsigned long long*)((unsigned short*)(ws + O_XH1) + (size_t)16384 + fb*512 + 256 + hbase);
    }

    for (int t = 0; t < TT; ++t) {
        f32x4 A0 = {0.f,0.f,0.f,0.f}, A1 = {0.f,0.f,0.f,0.f};

        if (L == 0) {
            short8 bx0 = ld8(xb), bx1 = ld8(xb + 32);
            A0 = __builtin_amdgcn_mfma_f32_16x16x32_bf16(a0[0], bx0, A0, 0,0,0);
            A1 = __builtin_amdgcn_mfma_f32_16x16x32_bf16(a1[0], bx0, A1, 0,0,0);
            A0 = __builtin_amdgcn_mfma_f32_16x16x32_bf16(a0[1], bx1, A0, 0,0,0);
            A1 = __builtin_amdgcn_mfma_f32_16x16x32_bf16(a1[1], bx1, A1, 0,0,0);

            if (wv == 0) pollLine(flags0, t, lane);
            __syncthreads();

            short8 b[8];
#pragma unroll
            for (int kk = 0; kk < 8; ++kk) b[kk] = ld8(hb + 32*kk);
#pragma unroll
            for (int kk = 0; kk < 8; ++kk) {
                A0 = __builtin_amdgcn_mfma_f32_16x16x32_bf16(a0[2+kk], b[kk], A0, 0,0,0);
                A1 = __builtin_amdgcn_mfma_f32_16x16x32_bf16(a1[2+kk], b[kk], A1, 0,0,0);
            }
        } else {
            if (wv == 0) pollTwo(flags0, t+1, flags1, t, lane);
            __syncthreads();

            short8 b[8];
#pragma unroll
            for (int kk = 0; kk < 8; ++kk) b[kk] = ld8(xh + 32*kk);
#pragma unroll
            for (int kk = 0; kk < 8; ++kk) {
                A0 = __builtin_amdgcn_mfma_f32_16x16x32_bf16(a0[kk], b[kk], A0, 0,0,0);
                A1 = __builtin_amdgcn_mfma_f32_16x16x32_bf16(a1[kk], b[kk], A1, 0,0,0);
            }
#pragma unroll
            for (int kk = 0; kk < 8; ++kk) b[kk] = ld8(xh + 256 + 32*kk);
#pragma unroll
            for (int kk = 0; kk < 8; ++kk) {
                A0 = __builtin_amdgcn_mfma_f32_16x16x32_bf16(a0[8+kk], b[kk], A0, 0,0,0);
                A1 = __builtin_amdgcn_mfma_f32_16x16x32_bf16(a1[8+kk], b[kk], A1, 0,0,0);
            }
        }

#pragma unroll
        for (int r = 0; r < 4; ++r) {
            float x0 = A0[r], y0 = __shfl_xor(x0, 32, 64);
            float x1 = A1[r], y1 = __shfl_xor(x1, 32, 64);
            float gi = (lo ? x0 : y0) + bi[r];
            float gf = (lo ? y0 : x0) + bf_[r];
            float gg = (lo ? x1 : y1) + bg[r];
            float go = (lo ? y1 : x1) + bo[r];
            float iv = sigm_(gi), fv = sigm_(gf), gv = tanhf_(gg), ov = sigm_(go);
            c[r]  = fv*c[r] + iv*gv;
            hv[r] = ov * tanhf_(c[r]);
        }

        unsigned long long w =
            (unsigned long long)pack2(hv[0], hv[1]) |
            ((unsigned long long)pack2(hv[2], hv[3]) << 32);

        if (L == 0) {
            if (lo) __hip_atomic_store(stA, w, __ATOMIC_RELAXED, __HIP_MEMORY_SCOPE_AGENT);
            else    __hip_atomic_store(stB, w, __ATOMIC_RELAXED, __HIP_MEMORY_SCOPE_AGENT);
        } else {
            if (lo) __hip_atomic_store(stA, w, __ATOMIC_RELAXED, __HIP_MEMORY_SCOPE_AGENT);
        }

        __syncthreads();
        if (tid == 0)
            __hip_atomic_store(myflag, t+1, __ATOMIC_RELAXED, __HIP_MEMORY_SCOPE_AGENT);

        xb += 2048; hb += 8192; xh += 16384;
        stA += (L ? 4096 : 2048);
        if (L == 0) stB += 4096;
    }

    if (lo) {
#pragma unroll
        for (int r = 0; r < 4; ++r) {
            out[HN_OFF + (size_t)L*8192 + fb*256 + hbase + r] = hv[r];
            out[CN_OFF + (size_t)L*8192 + fb*256 + hbase + r] = c[r];
        }
    }
}

// ---------------------------------------------------------------------------
// Mega-kernel: blocks 0..15 = r5 workers (passed at 12.1/12.08 ms in r5/r8);
// blocks 16..79 = MEMORY keepers streaming the static 8MB x region to hold
// the fabric/MALL clock up (the r8 FMA keepers proved core clocks are not
// the limiter; this tests the fabric clock).  Blocks 80..255 exit.
// Keepers read only static data and write nothing -> output = r5's.
// ---------------------------------------------------------------------------
__global__ __launch_bounds__(512, 2) void lstm_fused(char* ws,
                                                     const float* __restrict__ c0_in,
                                                     float* __restrict__ out)
{
    const int blk = blockIdx.x;
    int* done = (int*)(ws + O_D0) + DONE_IDX;

    if (blk < NBLK) {
        lstm_body<0>(blk, ws, c0_in, out);
        if (threadIdx.x == 0)
            __hip_atomic_fetch_add(done, 1, __ATOMIC_RELAXED, __HIP_MEMORY_SCOPE_AGENT);
        return;
    }
    if (blk < 2*NBLK) {
        lstm_body<1>(blk - NBLK, ws, c0_in, out);
        if (threadIdx.x == 0)
            __hip_atomic_fetch_add(done, 1, __ATOMIC_RELAXED, __HIP_MEMORY_SCOPE_AGENT);
        return;
    }
    if (blk >= 80) return;   // only 64 memory keepers

    // ---- memory keeper: stream x region (8MB, static after prep) ----
    __shared__ int sh;
    const uint4v* base = (const uint4v*)(ws + O_XBF);
    const unsigned nvec = 8388608u / 16u;            // 524288 float4-sized vecs
    unsigned idx = (((unsigned)(blk - 16) * 512u + threadIdx.x) * 7u) % nvec;
    uint4v acc = {0,0,0,0};
    for (int it = 0; it < (1<<14); ++it) {           // bounded: <= 8GB/block
#pragma unroll 8
        for (int k = 0; k < 64; ++k) {
            uint4v v = base[idx];
            acc.x += v.x; acc.y += v.y; acc.z += v.z; acc.w += v.w;
            idx += 32771u;                           // odd stride, walks region
            if (idx >= nvec) idx -= nvec;
        }
        if (threadIdx.x == 0)
            sh = __hip_atomic_load(done, __ATOMIC_RELAXED, __HIP_MEMORY_SCOPE_AGENT);
        __syncthreads();
        int d = sh;
        __syncthreads();
        if (d >= 2*NBLK) break;
    }
    asm volatile("" :: "v"(acc.x), "v"(acc.y), "v"(acc.z), "v"(acc.w));
}

// ---------------------------------------------------------------------------
// Fused dense head (identical to rounds 5/8).
// ---------------------------------------------------------------------------
__global__ __launch_bounds__(256) void head_kernel(const char* __restrict__ ws,
    const float* __restrict__ bd0, const float* __restrict__ bd1,
    const float* __restrict__ bout, float* __restrict__ out)
{
    const __hip_bfloat16* xh1 = (const __hip_bfloat16*)(ws + O_XH1);
    const float* Wd0T  = (const float*)(ws + O_WD0T);
    const float* Wd1T  = (const float*)(ws + O_WD1T);
    const float* WoutT = (const float*)(ws + O_WOUT);

    __shared__ float buf0[16][256];
    __shared__ float buf1[16][256];
    const int row0 = blockIdx.x * 16;
    const int tid = threadIdx.x;

#pragma unroll
    for (int i = 0; i < 16; ++i) {
        int r = row0 + i;
        int b = r >> 11, t = r & 2047;
        buf0[i][tid] = __bfloat162float(xh1[(size_t)(t+1)*16384 + b*512 + 256 + tid]);
    }
    __syncthreads();

    {   // stage 1: Linear+ReLU
        float acc[16];
        float bv = bd0[tid];
#pragma unroll
        for (int r = 0; r < 16; ++r) acc[r] = bv;
        for (int h = 0; h < 256; ++h) {
            float w = Wd0T[h*256 + tid];
#pragma unroll
            for (int r = 0; r < 16; ++r) acc[r] += w * buf0[r][h];
        }
        __syncthreads();
#pragma unroll
        for (int r = 0; r < 16; ++r) buf1[r][tid] = fmaxf(acc[r], 0.0f);
    }
    __syncthreads();

    {   // stage 2: Linear+ReLU
        float acc[16];
        float bv = bd1[tid];
#pragma unroll
        for (int r = 0; r < 16; ++r) acc[r] = bv;
        for (int h = 0; h < 256; ++h) {
            float w = Wd1T[h*256 + tid];
#pragma unroll
            for (int r = 0; r < 16; ++r) acc[r] += w * buf1[r][h];
        }
        __syncthreads();
#pragma unroll
        for (int r = 0; r < 16; ++r) buf0[r][tid] = fmaxf(acc[r], 0.0f);
    }
    __syncthreads();

    {   // stage 3: output Linear
        const int o = tid & 31;
        const int rr = tid >> 5;
        float a0 = bout[o], a1 = bout[o];
        for (int h = 0; h < 256; ++h) {
            float w = WoutT[h*32 + o];
            a0 += w * buf0[rr*2 + 0][h];
            a1 += w * buf0[rr*2 + 1][h];
        }
        out[(size_t)(row0 + rr*2 + 0)*32 + o] = a0;
        out[(size_t)(row0 + rr*2 + 1)*32 + o] = a1;
    }
}

// ---------------------------------------------------------------------------
extern "C" void kernel_launch(void* const* d_in, const int* in_sizes, int n_in,
                              void* d_out, int out_size, void* d_ws, size_t ws_size,
                              hipStream_t stream) {
    const float* x    = (const float*)d_in[0];
    const float* h0   = (const float*)d_in[1];
    const float* c0   = (const float*)d_in[2];
    const float* Wih0 = (const float*)d_in[3];
    const float* Whh0 = (const float*)d_in[4];
    const float* bih0 = (const float*)d_in[5];
    const float* bhh0 = (const float*)d_in[6];
    const float* Wih1 = (const float*)d_in[7];
    const float* Whh1 = (const float*)d_in[8];
    const float* bih1 = (const float*)d_in[9];
    const float* bhh1 = (const float*)d_in[10];
    const float* Wd0  = (const float*)d_in[11];
    const float* bd0  = (const float*)d_in[12];
    const float* Wd1  = (const float*)d_in[13];
    const float* bd1  = (const float*)d_in[14];
    const float* Wout = (const float*)d_in[15];
    const float* bout = (const float*)d_in[16];

    char* ws = (char*)d_ws;
    float* out = (float*)d_out;

    prep_kernel<<<20344, 256, 0, stream>>>(x, h0, Wih0, Whh0, bih0, bhh0,
                                           Wih1, Whh1, bih1, bhh1,
                                           Wd0, Wd1, Wout, ws);
    lstm_fused<<<256, 512, 0, stream>>>(ws, c0, out);
    head_kernel<<<4096, 256, 0, stream>>>(ws, bd0, bd1, bout, out);
}